// Round 2
// baseline (90.768 us; speedup 1.0000x reference)
//
#include <hip/hip_runtime.h>
#include <hip/hip_bf16.h>

typedef __attribute__((ext_vector_type(4))) float f32x4;
typedef __attribute__((ext_vector_type(8))) short s16x8;
typedef __attribute__((ext_vector_type(4))) short s16x4;

#define KVBLK 64
#define DHEAD 128
#define VSTR 72    // V^T LDS row stride in bf16 elems (144 B)

__device__ __forceinline__ short f2bf(float x) {
    __hip_bfloat16 h = __float2bfloat16(x);
    return *reinterpret_cast<short*>(&h);
}

// Flash-attention with KV-split. Each block: 32 q-rows (2 waves x 16), one KV chunk.
// S^T = K*Q^T with K fragments read DIRECTLY from global (no K LDS tile, no barrier).
// Partials (unnormalized O, m, l) to workspace when S>1; combine kernel merges.
__global__ __launch_bounds__(128, 4)
void attn_fwd(const float* __restrict__ Q, const float* __restrict__ K,
              const float* __restrict__ V, const int* __restrict__ VL,
              float* __restrict__ O, float* __restrict__ OP, float2* __restrict__ ML,
              int B, int n, int m, int S, int rows) {
    __shared__ short Vs[DHEAD * VSTR];   // V^T tile [dv][kv], XOR-swizzled

    const int tid  = threadIdx.x;
    const int lane = tid & 63;
    const int wid  = tid >> 6;     // 0..1
    const int g    = lane >> 4;    // 0..3
    const int qi   = lane & 15;

    const int nq = n >> 5;         // q-tiles of 32 rows
    int b, rest;
    if ((B & 7) == 0) {
        const int xcd = blockIdx.x & 7;
        const int sub = blockIdx.x >> 3;
        const int bpx = B >> 3;
        b    = xcd * bpx + (sub % bpx);
        rest = sub / bpx;
    } else {
        const int per = nq * S;
        b    = blockIdx.x / per;
        rest = blockIdx.x % per;
    }
    const int qt = rest / S;
    const int c  = rest - qt * S;

    const int vl = VL[b];
    const int nt = (vl + KVBLK - 1) >> 6;   // total KV tiles for this batch
    const int ct = (nt + S - 1) / S;        // tiles per chunk
    const int t0 = c * ct;
    const int t1 = min(nt, t0 + ct);

    const int rowbase = b * n + qt * 32 + wid * 16;  // global q-row base for this wave

    if (t0 >= t1) {
        // empty chunk: record (m=-inf, l=0), write nothing else
        if (S > 1 && g == 0) ML[(size_t)c * rows + rowbase + qi] = make_float2(-1e30f, 0.f);
        return;
    }

    const float* Qb = Q + (size_t)rowbase * DHEAD;
    const float* Kb = K + (size_t)b * m * DHEAD;
    const float* Vb = V + (size_t)b * m * DHEAD;

    // ---- Q fragments in registers, pre-scaled by 1/sqrt(d)*log2(e) (base-2 softmax) ----
    const float qsc = 0.08838834764831845f * 1.4426950408889634f;
    s16x8 qf[4];
    {
        const float* qp = Qb + qi * DHEAD + g * 8;
        #pragma unroll
        for (int kk = 0; kk < 4; ++kk) {
            f32x4 a = *reinterpret_cast<const f32x4*>(qp + kk * 32);
            f32x4 cc = *reinterpret_cast<const f32x4*>(qp + kk * 32 + 4);
            s16x8 s;
            #pragma unroll
            for (int j = 0; j < 4; ++j) { s[j] = f2bf(a[j] * qsc); s[4 + j] = f2bf(cc[j] * qsc); }
            qf[kk] = s;
        }
    }

    // per-lane V^T read bases (element offsets, swizzle folded in)
    int voff[8];
    #pragma unroll
    for (int dg = 0; dg < 8; ++dg) {
        const int row = qi + (dg << 4);
        voff[dg] = row * VSTR + ((g << 2) ^ (((row >> 3) & 3) << 2));
    }

    f32x4 Oacc[8];
    #pragma unroll
    for (int dg = 0; dg < 8; ++dg) Oacc[dg] = 0.f;
    float mrun = -1e30f, lrun = 0.f;

    #pragma unroll 1
    for (int t = t0; t < t1; ++t) {
        const int base = t << 6;
        __syncthreads();   // all waves done reading previous Vs
        // ---- stage V tile transposed: V^T[dv][kv], swizzled columns ----
        {
            const float* vp = Vb + (size_t)base * DHEAD;
            #pragma unroll
            for (int i = 0; i < 4; ++i) {
                const int cth = tid + (i << 7);
                const int rq  = cth >> 5;    // kv quad 0..15
                const int dq  = cth & 31;    // dv quad 0..31
                const float* src = vp + (rq * 4) * DHEAD + dq * 4;
                f32x4 r0 = *reinterpret_cast<const f32x4*>(src);
                f32x4 r1 = *reinterpret_cast<const f32x4*>(src + DHEAD);
                f32x4 r2 = *reinterpret_cast<const f32x4*>(src + 2 * DHEAD);
                f32x4 r3 = *reinterpret_cast<const f32x4*>(src + 3 * DHEAD);
                #pragma unroll
                for (int jj = 0; jj < 4; ++jj) {
                    const int dvr = dq * 4 + jj;
                    s16x4 s;
                    s[0] = f2bf(r0[jj]); s[1] = f2bf(r1[jj]);
                    s[2] = f2bf(r2[jj]); s[3] = f2bf(r3[jj]);
                    const int eoff = dvr * VSTR + ((rq << 2) ^ (((dvr >> 3) & 3) << 2));
                    *reinterpret_cast<s16x4*>(&Vs[eoff]) = s;
                }
            }
        }

        // ---- S^T = K * Q^T, K fragments direct from global (overlaps V ds_write drain) ----
        f32x4 Sacc[4];
        #pragma unroll
        for (int s = 0; s < 4; ++s) Sacc[s] = 0.f;
        #pragma unroll
        for (int s = 0; s < 4; ++s) {
            const float* kp = Kb + (size_t)(base + s * 16 + qi) * DHEAD + (g << 3);
            #pragma unroll
            for (int kk = 0; kk < 4; ++kk) {
                f32x4 a  = *reinterpret_cast<const f32x4*>(kp + kk * 32);
                f32x4 cc = *reinterpret_cast<const f32x4*>(kp + kk * 32 + 4);
                s16x8 kf;
                #pragma unroll
                for (int j = 0; j < 4; ++j) { kf[j] = f2bf(a[j]); kf[4 + j] = f2bf(cc[j]); }
                Sacc[s] = __builtin_amdgcn_mfma_f32_16x16x32_bf16(kf, qf[kk], Sacc[s], 0, 0, 0);
            }
        }
        __syncthreads();   // Vs ready

        // ---- valid_length mask ----
        const int kvrem = vl - base;
        if (kvrem < KVBLK) {
            #pragma unroll
            for (int s = 0; s < 4; ++s)
                #pragma unroll
                for (int r = 0; r < 4; ++r)
                    if (s * 16 + g * 4 + r >= kvrem) Sacc[s][r] = -1e30f;
        }

        // ---- online softmax (state per lane for q = qi, replicated x4 groups) ----
        float tmax = -1e30f;
        #pragma unroll
        for (int s = 0; s < 4; ++s)
            #pragma unroll
            for (int r = 0; r < 4; ++r) tmax = fmaxf(tmax, Sacc[s][r]);
        tmax = fmaxf(tmax, __shfl_xor(tmax, 16));
        tmax = fmaxf(tmax, __shfl_xor(tmax, 32));
        const float mnew = fmaxf(mrun, tmax);
        const float corr = __builtin_amdgcn_exp2f(mrun - mnew);

        float psum = 0.f;
        #pragma unroll
        for (int s = 0; s < 4; ++s)
            #pragma unroll
            for (int r = 0; r < 4; ++r) {
                const float e = __builtin_amdgcn_exp2f(Sacc[s][r] - mnew);
                Sacc[s][r] = e; psum += e;
            }
        psum += __shfl_xor(psum, 16);
        psum += __shfl_xor(psum, 32);
        lrun = lrun * corr + psum;
        mrun = mnew;

        // pack P -> bf16 A-fragments (kv-permutation consistent with V^T reads)
        s16x8 pa[2];
        #pragma unroll
        for (int h = 0; h < 2; ++h)
            #pragma unroll
            for (int r = 0; r < 4; ++r) {
                pa[h][r]     = f2bf(Sacc[2 * h][r]);
                pa[h][4 + r] = f2bf(Sacc[2 * h + 1][r]);
            }

        // rescale O accumulators (rows q' = 4g+r need corr from lane q')
        const float rr0 = __shfl(corr, g * 4 + 0);
        const float rr1 = __shfl(corr, g * 4 + 1);
        const float rr2 = __shfl(corr, g * 4 + 2);
        const float rr3 = __shfl(corr, g * 4 + 3);
        #pragma unroll
        for (int dg = 0; dg < 8; ++dg) {
            Oacc[dg][0] *= rr0; Oacc[dg][1] *= rr1;
            Oacc[dg][2] *= rr2; Oacc[dg][3] *= rr3;
        }

        // ---- O += P * V ----
        #pragma unroll
        for (int dg = 0; dg < 8; ++dg) {
            #pragma unroll
            for (int kk = 0; kk < 2; ++kk) {
                s16x4 v0 = *reinterpret_cast<const s16x4*>(&Vs[voff[dg] + (kk << 5)]);
                s16x4 v1 = *reinterpret_cast<const s16x4*>(&Vs[voff[dg] + (kk << 5) + 16]);
                s16x8 vf;
                vf[0] = v0[0]; vf[1] = v0[1]; vf[2] = v0[2]; vf[3] = v0[3];
                vf[4] = v1[0]; vf[5] = v1[1]; vf[6] = v1[2]; vf[7] = v1[3];
                Oacc[dg] = __builtin_amdgcn_mfma_f32_16x16x32_bf16(pa[kk], vf, Oacc[dg], 0, 0, 0);
            }
        }
    }

    if (S > 1) {
        // ---- write unnormalized partials + (m,l) ----
        if (g == 0) ML[(size_t)c * rows + rowbase + qi] = make_float2(mrun, lrun);
        float* Op = OP + ((size_t)c * rows + rowbase) * DHEAD;
        #pragma unroll
        for (int dg = 0; dg < 8; ++dg) {
            Op[(g * 4 + 0) * DHEAD + dg * 16 + qi] = Oacc[dg][0];
            Op[(g * 4 + 1) * DHEAD + dg * 16 + qi] = Oacc[dg][1];
            Op[(g * 4 + 2) * DHEAD + dg * 16 + qi] = Oacc[dg][2];
            Op[(g * 4 + 3) * DHEAD + dg * 16 + qi] = Oacc[dg][3];
        }
    } else {
        // ---- direct: normalize and write O ----
        const float linv = 1.0f / lrun;
        const float l0 = __shfl(linv, g * 4 + 0);
        const float l1 = __shfl(linv, g * 4 + 1);
        const float l2 = __shfl(linv, g * 4 + 2);
        const float l3 = __shfl(linv, g * 4 + 3);
        float* Ob = O + (size_t)rowbase * DHEAD;
        #pragma unroll
        for (int dg = 0; dg < 8; ++dg) {
            Ob[(g * 4 + 0) * DHEAD + dg * 16 + qi] = Oacc[dg][0] * l0;
            Ob[(g * 4 + 1) * DHEAD + dg * 16 + qi] = Oacc[dg][1] * l1;
            Ob[(g * 4 + 2) * DHEAD + dg * 16 + qi] = Oacc[dg][2] * l2;
            Ob[(g * 4 + 3) * DHEAD + dg * 16 + qi] = Oacc[dg][3] * l3;
        }
    }
}

// merge S partial (O, m, l) per q-row: one block per row, one thread per dv elem
__global__ __launch_bounds__(128)
void attn_combine(const float* __restrict__ OP, const float2* __restrict__ ML,
                  float* __restrict__ O, int S, int rows) {
    const int row = blockIdx.x;
    const int t   = threadIdx.x;
    float M = -1e30f;
    for (int s = 0; s < S; ++s) M = fmaxf(M, ML[(size_t)s * rows + row].x);
    float L = 0.f, acc = 0.f;
    for (int s = 0; s < S; ++s) {
        const float2 ml = ML[(size_t)s * rows + row];
        if (ml.y > 0.f) {
            const float w = exp2f(ml.x - M);
            L += ml.y * w;
            acc += w * OP[((size_t)s * rows + row) * DHEAD + t];
        }
    }
    O[(size_t)row * DHEAD + t] = acc / L;
}

extern "C" void kernel_launch(void* const* d_in, const int* in_sizes, int n_in,
                              void* d_out, int out_size, void* d_ws, size_t ws_size,
                              hipStream_t stream) {
    const float* Q  = (const float*)d_in[0];
    const float* K  = (const float*)d_in[1];
    const float* V  = (const float*)d_in[2];
    const int*   VL = (const int*)d_in[3];
    float* O = (float*)d_out;

    const int B = in_sizes[3];
    const int n = in_sizes[0] / (B * DHEAD);
    const int m = in_sizes[1] / (B * DHEAD);
    const int rows = B * n;

    // pick KV-split factor by available workspace
    const size_t per_chunk = (size_t)rows * (DHEAD * 4 + 8);
    int S = 1;
    if (ws_size >= 4 * per_chunk) S = 4;
    else if (ws_size >= 2 * per_chunk) S = 2;

    float*  OP = (float*)d_ws;
    float2* ML = (float2*)((char*)d_ws + (size_t)S * rows * DHEAD * 4);

    const int grid = B * (n / 32) * S;
    attn_fwd<<<grid, 128, 0, stream>>>(Q, K, V, VL, O, OP, ML, B, n, m, S, rows);
    if (S > 1)
        attn_combine<<<rows, 128, 0, stream>>>(OP, ML, O, S, rows);
}

// Round 3
// 46.968 us; speedup vs baseline: 1.9325x; 1.9325x over previous
//
#include <hip/hip_runtime.h>
#include <hip/hip_bf16.h>

typedef __attribute__((ext_vector_type(4))) float f32x4;
typedef __attribute__((ext_vector_type(8))) short s16x8;
typedef __attribute__((ext_vector_type(4))) short s16x4;

#define KVBLK 32
#define DHEAD 128
#define KSTR 136   // K LDS row stride in bf16 elems (272 B)
#define VSTR 40    // V^T LDS row stride in bf16 elems (80 B)

__device__ __forceinline__ short f2bf(float x) {
    __hip_bfloat16 h = __float2bfloat16(x);
    return *reinterpret_cast<short*>(&h);
}

// Flash attention, cyclic KV-split S. Block = 2 waves x 16 q-rows, KVBLK=32.
// K and V^T staged in LDS (shared by both waves). Partials to d_ws; combine merges.
__global__ __launch_bounds__(128, 4)
void attn_fwd(const float* __restrict__ Q, const float* __restrict__ K,
              const float* __restrict__ V, const int* __restrict__ VL,
              float* __restrict__ O, float* __restrict__ OP, float2* __restrict__ ML,
              int B, int n, int m, int S, int rows) {
    __shared__ short Ks[KVBLK * KSTR];   // 8704 B
    __shared__ short Vs[DHEAD * VSTR];   // 10240 B  (total 18944 B -> 8 blocks/CU)

    const int tid  = threadIdx.x;
    const int lane = tid & 63;
    const int wid  = tid >> 6;     // 0..1
    const int g    = lane >> 4;    // 0..3
    const int qi   = lane & 15;

    const int nq = n >> 5;         // q-tiles of 32 rows
    int b, rest;
    if ((B & 7) == 0) {
        const int xcd = blockIdx.x & 7;
        const int sub = blockIdx.x >> 3;
        const int bpx = B >> 3;
        b    = xcd * bpx + (sub % bpx);
        rest = sub / bpx;
    } else {
        const int per = nq * S;
        b    = blockIdx.x / per;
        rest = blockIdx.x % per;
    }
    const int qt = rest / S;
    const int c  = rest - qt * S;

    const int vl = VL[b];
    const int nt = (vl + KVBLK - 1) / KVBLK;   // total KV tiles for this batch
    const int rowbase = b * n + qt * 32 + wid * 16;

    if (c >= nt) {   // empty chunk (cyclic: chunk c owns tiles c, c+S, ...)
        if (g == 0) ML[(size_t)c * rows + rowbase + qi] = make_float2(-1e30f, 0.f);
        return;
    }

    const float* Qb = Q + (size_t)rowbase * DHEAD;
    const float* Kb = K + (size_t)b * m * DHEAD;
    const float* Vb = V + (size_t)b * m * DHEAD;

    // ---- Q fragments, pre-scaled by 1/sqrt(d)*log2(e) ----
    const float qsc = 0.08838834764831845f * 1.4426950408889634f;
    s16x8 qf[4];
    {
        const float* qp = Qb + qi * DHEAD + g * 8;
        #pragma unroll
        for (int kk = 0; kk < 4; ++kk) {
            f32x4 a  = *reinterpret_cast<const f32x4*>(qp + kk * 32);
            f32x4 cc = *reinterpret_cast<const f32x4*>(qp + kk * 32 + 4);
            s16x8 s;
            #pragma unroll
            for (int j = 0; j < 4; ++j) { s[j] = f2bf(a[j] * qsc); s[4 + j] = f2bf(cc[j] * qsc); }
            qf[kk] = s;
        }
    }

    // per-lane V^T read bases (element offsets, swizzle folded in)
    int voff[8];
    #pragma unroll
    for (int dg = 0; dg < 8; ++dg) {
        const int row = qi + (dg << 4);
        voff[dg] = row * VSTR + ((g << 2) ^ (((row >> 3) & 3) << 2));
    }
    const int kbase = qi * KSTR + (g << 3);

    f32x4 Oacc[8];
    #pragma unroll
    for (int dg = 0; dg < 8; ++dg) Oacc[dg] = 0.f;
    float mrun = -1e30f, lrun = 0.f;

    #pragma unroll 1
    for (int t = c; t < nt; t += S) {
        const int base = t * KVBLK;
        __syncthreads();   // everyone done reading previous tile
        // ---- stage K tile 32x128 -> bf16 LDS ----
        {
            const float* kp = Kb + (size_t)base * DHEAD;
            #pragma unroll
            for (int i = 0; i < 4; ++i) {
                const int cc2 = tid + (i << 7);
                const int row = cc2 >> 4;
                const int d0  = (cc2 & 15) << 3;
                f32x4 a  = *reinterpret_cast<const f32x4*>(kp + row * DHEAD + d0);
                f32x4 cc = *reinterpret_cast<const f32x4*>(kp + row * DHEAD + d0 + 4);
                s16x8 s;
                #pragma unroll
                for (int j = 0; j < 4; ++j) { s[j] = f2bf(a[j]); s[4 + j] = f2bf(cc[j]); }
                *reinterpret_cast<s16x8*>(&Ks[row * KSTR + d0]) = s;
            }
        }
        // ---- stage V tile transposed: V^T[dv][kv], swizzled ----
        {
            const float* vp = Vb + (size_t)base * DHEAD;
            #pragma unroll
            for (int i = 0; i < 2; ++i) {
                const int cth = tid + (i << 7);
                const int rq  = cth >> 5;    // kv quad 0..7
                const int dq  = cth & 31;    // dv quad 0..31
                const float* src = vp + (rq * 4) * DHEAD + dq * 4;
                f32x4 r0 = *reinterpret_cast<const f32x4*>(src);
                f32x4 r1 = *reinterpret_cast<const f32x4*>(src + DHEAD);
                f32x4 r2 = *reinterpret_cast<const f32x4*>(src + 2 * DHEAD);
                f32x4 r3 = *reinterpret_cast<const f32x4*>(src + 3 * DHEAD);
                #pragma unroll
                for (int jj = 0; jj < 4; ++jj) {
                    const int dvr = dq * 4 + jj;
                    s16x4 s;
                    s[0] = f2bf(r0[jj]); s[1] = f2bf(r1[jj]);
                    s[2] = f2bf(r2[jj]); s[3] = f2bf(r3[jj]);
                    const int eoff = dvr * VSTR + ((rq << 2) ^ (((dvr >> 3) & 3) << 2));
                    *reinterpret_cast<s16x4*>(&Vs[eoff]) = s;
                }
            }
        }
        __syncthreads();

        // ---- S^T = K * Q^T : rows kv = 16s+4g+r, col q = qi ----
        f32x4 Sacc[2];
        #pragma unroll
        for (int s = 0; s < 2; ++s) Sacc[s] = 0.f;
        #pragma unroll
        for (int s = 0; s < 2; ++s) {
            #pragma unroll
            for (int kk = 0; kk < 4; ++kk) {
                s16x8 kf = *reinterpret_cast<const s16x8*>(&Ks[kbase + s * 16 * KSTR + kk * 32]);
                Sacc[s] = __builtin_amdgcn_mfma_f32_16x16x32_bf16(kf, qf[kk], Sacc[s], 0, 0, 0);
            }
        }

        // ---- valid_length mask ----
        const int kvrem = vl - base;
        if (kvrem < KVBLK) {
            #pragma unroll
            for (int s = 0; s < 2; ++s)
                #pragma unroll
                for (int r = 0; r < 4; ++r)
                    if (s * 16 + g * 4 + r >= kvrem) Sacc[s][r] = -1e30f;
        }

        // ---- online softmax (state per lane for q = qi, replicated x4 groups) ----
        float tmax = -1e30f;
        #pragma unroll
        for (int s = 0; s < 2; ++s)
            #pragma unroll
            for (int r = 0; r < 4; ++r) tmax = fmaxf(tmax, Sacc[s][r]);
        tmax = fmaxf(tmax, __shfl_xor(tmax, 16));
        tmax = fmaxf(tmax, __shfl_xor(tmax, 32));
        const float mnew = fmaxf(mrun, tmax);
        const float corr = __builtin_amdgcn_exp2f(mrun - mnew);

        float psum = 0.f;
        #pragma unroll
        for (int s = 0; s < 2; ++s)
            #pragma unroll
            for (int r = 0; r < 4; ++r) {
                const float e = __builtin_amdgcn_exp2f(Sacc[s][r] - mnew);
                Sacc[s][r] = e; psum += e;
            }
        psum += __shfl_xor(psum, 16);
        psum += __shfl_xor(psum, 32);
        lrun = lrun * corr + psum;
        mrun = mnew;

        // pack P -> bf16 A-fragment (kv order consistent with V^T reads)
        s16x8 pa;
        #pragma unroll
        for (int r = 0; r < 4; ++r) {
            pa[r]     = f2bf(Sacc[0][r]);
            pa[4 + r] = f2bf(Sacc[1][r]);
        }

        // rescale O accumulators (rows q' = 4g+r need corr from lane q')
        const float rr0 = __shfl(corr, g * 4 + 0);
        const float rr1 = __shfl(corr, g * 4 + 1);
        const float rr2 = __shfl(corr, g * 4 + 2);
        const float rr3 = __shfl(corr, g * 4 + 3);
        #pragma unroll
        for (int dg = 0; dg < 8; ++dg) {
            Oacc[dg][0] *= rr0; Oacc[dg][1] *= rr1;
            Oacc[dg][2] *= rr2; Oacc[dg][3] *= rr3;
        }

        // ---- O += P * V ----
        #pragma unroll
        for (int dg = 0; dg < 8; ++dg) {
            s16x4 v0 = *reinterpret_cast<const s16x4*>(&Vs[voff[dg]]);
            s16x4 v1 = *reinterpret_cast<const s16x4*>(&Vs[voff[dg] + 16]);
            s16x8 vf;
            vf[0] = v0[0]; vf[1] = v0[1]; vf[2] = v0[2]; vf[3] = v0[3];
            vf[4] = v1[0]; vf[5] = v1[1]; vf[6] = v1[2]; vf[7] = v1[3];
            Oacc[dg] = __builtin_amdgcn_mfma_f32_16x16x32_bf16(pa, vf, Oacc[dg], 0, 0, 0);
        }
    }

    if (S > 1) {
        if (g == 0) ML[(size_t)c * rows + rowbase + qi] = make_float2(mrun, lrun);
        float* Op = OP + ((size_t)c * rows + rowbase) * DHEAD;
        #pragma unroll
        for (int dg = 0; dg < 8; ++dg) {
            Op[(g * 4 + 0) * DHEAD + dg * 16 + qi] = Oacc[dg][0];
            Op[(g * 4 + 1) * DHEAD + dg * 16 + qi] = Oacc[dg][1];
            Op[(g * 4 + 2) * DHEAD + dg * 16 + qi] = Oacc[dg][2];
            Op[(g * 4 + 3) * DHEAD + dg * 16 + qi] = Oacc[dg][3];
        }
    } else {
        const float linv = 1.0f / lrun;
        const float l0 = __shfl(linv, g * 4 + 0);
        const float l1 = __shfl(linv, g * 4 + 1);
        const float l2 = __shfl(linv, g * 4 + 2);
        const float l3 = __shfl(linv, g * 4 + 3);
        float* Ob = O + (size_t)rowbase * DHEAD;
        #pragma unroll
        for (int dg = 0; dg < 8; ++dg) {
            Ob[(g * 4 + 0) * DHEAD + dg * 16 + qi] = Oacc[dg][0] * l0;
            Ob[(g * 4 + 1) * DHEAD + dg * 16 + qi] = Oacc[dg][1] * l1;
            Ob[(g * 4 + 2) * DHEAD + dg * 16 + qi] = Oacc[dg][2] * l2;
            Ob[(g * 4 + 3) * DHEAD + dg * 16 + qi] = Oacc[dg][3] * l3;
        }
    }
}

// merge S partials (O, m, l) per q-row: one block per row, one thread per dv elem
__global__ __launch_bounds__(128)
void attn_combine(const float* __restrict__ OP, const float2* __restrict__ ML,
                  float* __restrict__ O, int S, int rows) {
    const int row = blockIdx.x;
    const int t   = threadIdx.x;
    float M = -1e30f;
    for (int s = 0; s < S; ++s) M = fmaxf(M, ML[(size_t)s * rows + row].x);
    float L = 0.f, acc = 0.f;
    for (int s = 0; s < S; ++s) {
        const float2 ml = ML[(size_t)s * rows + row];
        if (ml.y > 0.f) {
            const float w = exp2f(ml.x - M);
            L += ml.y * w;
            acc += w * OP[((size_t)s * rows + row) * DHEAD + t];
        }
    }
    O[(size_t)row * DHEAD + t] = acc / L;
}

extern "C" void kernel_launch(void* const* d_in, const int* in_sizes, int n_in,
                              void* d_out, int out_size, void* d_ws, size_t ws_size,
                              hipStream_t stream) {
    const float* Q  = (const float*)d_in[0];
    const float* K  = (const float*)d_in[1];
    const float* V  = (const float*)d_in[2];
    const int*   VL = (const int*)d_in[3];
    float* O = (float*)d_out;

    const int B = in_sizes[3];
    const int n = in_sizes[0] / (B * DHEAD);
    const int m = in_sizes[1] / (B * DHEAD);
    const int rows = B * n;

    const size_t per_chunk = (size_t)rows * (DHEAD * 4 + 8);
    int S = 1;
    if (ws_size >= 4 * per_chunk) S = 4;
    else if (ws_size >= 2 * per_chunk) S = 2;

    float*  OP = (float*)d_ws;
    float2* ML = (float2*)((char*)d_ws + (size_t)S * rows * DHEAD * 4);

    const int grid = B * (n / 32) * S;
    attn_fwd<<<grid, 128, 0, stream>>>(Q, K, V, VL, O, OP, ML, B, n, m, S, rows);
    if (S > 1)
        attn_combine<<<rows, 128, 0, stream>>>(OP, ML, O, S, rows);
}